// Round 18
// baseline (223.158 us; speedup 1.0000x reference)
//
#include <hip/hip_runtime.h>
#include <hip/hip_bf16.h>

// MessagePassingLayer, Round 18: barrier-free band-local edge kernel.
// R17 post-mortem: same-reg gather reissue serialized (edge 128->146). Five
// failed pipeline attempts all hit the same wall: the 2-barrier/tile lockstep
// re-exposes any single wave's stall to all waves (m233: stage+vmcnt+barrier
// is ~72% of a 2-phase loop). This round removes the barriers entirely:
//  - wave w owns edges [16w,16w+16) END-TO-END (both layers band-local).
//  - layer-1: M=16 own edges x N=64 ch x K=160; A-frags from own X rows
//    (staging was already band-aligned); B-frags from W1L LDS table (20KB).
//  - layer-2 B-frags from global (L1-resident 8KB) -> LDS 51.7KB, 3 blk/CU
//    = 12 independent self-paced waves/CU (attn-style regime; setprio pays).
//  - ZERO per-tile barriers; wave-local lgkmcnt(0) only. One __syncthreads
//    at start for W1L. Grid = 768 = exactly 3/CU resident, balanced split.
// Falsifiers: WRITE>48.5MB (spill), absmax>>0.031 (layout bug), edge>=128us
// (barriers weren't the cost -> R13 is the plateau).

typedef __attribute__((ext_vector_type(8))) short s16x8;     // MFMA A/B frag
typedef __attribute__((ext_vector_type(4))) float f32x4;     // MFMA C/D frag
typedef __attribute__((ext_vector_type(8))) unsigned short u16x8;

#define SXE 168   // edge X tile row stride (bf16)
#define SXN 136   // node X tile row stride
#define SX2 72    // activation/message tile stride
#define NBLK_EDGE 768   // 3 blocks/CU x 256 CU (LDS 51.7KB -> 3 resident)
#define S1_CHUNK 4096
#define S2_CAP 10240   // max records per bucket for LDS sort (mean ~8163)

__device__ __forceinline__ unsigned short f2bf(float f) {   // native RNE cvt
  __hip_bfloat16 b = __float2bfloat16(f);
  return __builtin_bit_cast(unsigned short, b);
}
__device__ __forceinline__ float bf2f(unsigned short s) {
  unsigned int u = ((unsigned int)s) << 16;
  return __builtin_bit_cast(float, u);
}
__device__ __forceinline__ u16x8 pack8(const float4 a, const float4 b) {
  u16x8 r;
  r[0] = f2bf(a.x); r[1] = f2bf(a.y); r[2] = f2bf(a.z); r[3] = f2bf(a.w);
  r[4] = f2bf(b.x); r[5] = f2bf(b.y); r[6] = f2bf(b.z); r[7] = f2bf(b.w);
  return r;
}
// wave-local LDS ordering (no cross-wave barrier needed in band-local design)
__device__ __forceinline__ void wait_lds() {
  __builtin_amdgcn_sched_barrier(0);
  asm volatile("s_waitcnt lgkmcnt(0)" ::: "memory");
  __builtin_amdgcn_sched_barrier(0);
}

// ---------------- fused pre-pass: conv_bf16 + pack_weights + bucket hist ----------------
__global__ void prep(const float* __restrict__ h, unsigned short* __restrict__ hb, long long htot,
                     const float* __restrict__ eW1, const float* __restrict__ eW2,
                     const float* __restrict__ uW1, const float* __restrict__ uW2,
                     unsigned short* __restrict__ w1p, unsigned short* __restrict__ w2p,
                     unsigned short* __restrict__ uw1p, unsigned short* __restrict__ uw2p,
                     const int* __restrict__ ei, int* __restrict__ bhist, int E,
                     int conv_blocks) {
  __shared__ int lh[256];
  const int b = blockIdx.x;
  const int tid = threadIdx.x;
  if (b < conv_blocks) {
    const long long i = ((long long)b * 256 + tid) * 4;
    if (i + 3 < htot) {
      const float4 v = *(const float4*)(h + i);
      ushort4 o;
      o.x = f2bf(v.x); o.y = f2bf(v.y); o.z = f2bf(v.z); o.w = f2bf(v.w);
      *(ushort4*)(hb + i) = o;
    } else {
      for (long long j = i; j < htot; ++j) hb[j] = f2bf(h[j]);
    }
  } else if (b < conv_blocks + 13) {
    const int t2 = (b - conv_blocks) * 256 + tid;
    if (t2 < 52 * 64) {
      const int c = t2 & 63;
      int kg = t2 >> 6;
      const float* src;
      unsigned short* dst;
      if (kg < 20)      { src = eW1; dst = w1p; }
      else if (kg < 28) { src = eW2; dst = w2p; kg -= 20; }
      else if (kg < 44) { src = uW1; dst = uw1p; kg -= 28; }
      else              { src = uW2; dst = uw2p; kg -= 44; }
#pragma unroll
      for (int e = 0; e < 8; ++e)
        dst[(size_t)(kg * 64 + c) * 8 + e] = f2bf(src[(size_t)(kg * 8 + e) * 64 + c]);
    }
  } else {
    // 196-bin bucket histogram of tgt>>9 (LDS-binned)
    lh[tid] = 0;
    __syncthreads();
    const int hbk = b - conv_blocks - 13;   // 1024 hist blocks
    for (long long e = (long long)hbk * 256 + tid; e < E; e += 1024LL * 256)
      atomicAdd(&lh[ei[E + e] >> 9], 1);
    __syncthreads();
    if (lh[tid]) atomicAdd(&bhist[tid], lh[tid]);
  }
}

// exclusive scan of <=256 bucket counts -> bstart, bcursor
__global__ void bscan(const int* __restrict__ bhist, int* __restrict__ bstart,
                      int* __restrict__ bcursor, int nbuck) {
  __shared__ int s[256];
  const int tid = threadIdx.x;
  const int v = (tid < nbuck) ? bhist[tid] : 0;
  s[tid] = v;
  __syncthreads();
  for (int off = 1; off < 256; off <<= 1) {
    int t = (tid >= off) ? s[tid - off] : 0;
    __syncthreads();
    s[tid] += t;
    __syncthreads();
  }
  const int excl = s[tid] - v;
  if (tid < nbuck) { bstart[tid] = excl; bcursor[tid] = excl; }
}

// S1: coarse bucket scatter. Block-local grouping -> same-L2 line merging.
__global__ __launch_bounds__(256)
void bucket_scatter(const int* __restrict__ ei, int* __restrict__ bcursor,
                    unsigned long long* __restrict__ bufA, int E) {
  __shared__ int lhist[256], lbase[256], lcur[256];
  const int tid = threadIdx.x;
  const long long c0 = (long long)blockIdx.x * S1_CHUNK;

  lhist[tid] = 0;
  __syncthreads();

  unsigned long long rec[16];
  int bk[16];
#pragma unroll
  for (int j = 0; j < 16; ++j) {
    const long long e = c0 + j * 256 + tid;      // coalesced
    if (e < E) {
      const int t = ei[E + e];
      const int s = ei[e];
      rec[j] = (unsigned long long)(unsigned int)e |
               ((unsigned long long)(unsigned int)t << 21) |
               ((unsigned long long)(unsigned int)s << 38);
      bk[j] = t >> 9;
      atomicAdd(&lhist[bk[j]], 1);
    } else {
      bk[j] = -1;
    }
  }
  __syncthreads();

  if (lhist[tid] > 0) lbase[tid] = atomicAdd(&bcursor[tid], lhist[tid]);
  lcur[tid] = 0;
  __syncthreads();

#pragma unroll
  for (int j = 0; j < 16; ++j) {
    if (bk[j] >= 0) {
      const int pos = lbase[bk[j]] + atomicAdd(&lcur[bk[j]], 1);
      bufA[pos] = rec[j];   // contiguous within (block, bucket) group
    }
  }
}

// S2: per-bucket LDS counting sort by tgt&511 -> exact-tgt contiguity.
__global__ __launch_bounds__(256)
void bucket_sort(const unsigned long long* __restrict__ bufA,
                 const int* __restrict__ bstart, const int* __restrict__ bhist,
                 unsigned long long* __restrict__ aoe) {
  __shared__ unsigned long long srec[S2_CAP];   // 80 KB
  __shared__ int khist[512];
  __shared__ int sdata[256];
  const int b = blockIdx.x;
  const int tid = threadIdx.x;
  const int s0 = bstart[b];
  const int nb = bhist[b];

  if (nb > S2_CAP) {   // pathological bucket: pass through unsorted (still correct)
    for (int i = tid; i < nb; i += 256) aoe[s0 + i] = bufA[s0 + i];
    return;
  }

  khist[tid] = 0;
  khist[tid + 256] = 0;
  __syncthreads();
  for (int i = tid; i < nb; i += 256) {
    const unsigned long long r = bufA[s0 + i];
    atomicAdd(&khist[(int)((r >> 21) & 511)], 1);
  }
  __syncthreads();

  // exclusive scan over 512 bins (thread owns bins 2t, 2t+1)
  const int a0 = khist[2 * tid], a1 = khist[2 * tid + 1];
  const int sum = a0 + a1;
  sdata[tid] = sum;
  __syncthreads();
  for (int off = 1; off < 256; off <<= 1) {
    int t = (tid >= off) ? sdata[tid - off] : 0;
    __syncthreads();
    sdata[tid] += t;
    __syncthreads();
  }
  const int excl = sdata[tid] - sum;
  khist[2 * tid] = excl;           // khist becomes the scatter cursor
  khist[2 * tid + 1] = excl + a0;
  __syncthreads();

  for (int i = tid; i < nb; i += 256) {
    const unsigned long long r = bufA[s0 + i];   // L2-hot re-read
    const int pos = atomicAdd(&khist[(int)((r >> 21) & 511)], 1);
    srec[pos] = r;
  }
  __syncthreads();
  for (int i = tid; i < nb; i += 256) aoe[s0 + i] = srec[i];   // coalesced
}

// ---------------- fused edge MLP: barrier-free, band-local ----------------
// Fragment maps (mfma_f32_16x16x32_bf16, lane l: g=l>>4, r=l&15):
//   A[m][k]: m=r, k=8g+e   B[k][n]: n=r, k=8g+e   D[m][n]: n=r, m=4g+i
// Wave w owns edges [16w,16w+16) of every tile; no cross-wave data flow.
__global__ __launch_bounds__(256, 3)
void edge_mlp_fused(const unsigned short* __restrict__ hb, const float* __restrict__ ef,
                    const unsigned short* __restrict__ w1p, const float* __restrict__ b1,
                    const unsigned short* __restrict__ w2p, const float* __restrict__ b2,
                    const unsigned long long* __restrict__ aoe, float* __restrict__ agg,
                    int E, int ntiles, int nblk) {
  __shared__ unsigned short X[64 * SXE];      // 21.5 KB input tile
  __shared__ unsigned short X2[64 * SX2];     // 9.2 KB acts, then message tile
  __shared__ unsigned short W1L[160 * 64];    // 20 KB W1 fragment table
  __shared__ int tgts[2][64];

  const int tid = threadIdx.x;
  const int w = tid >> 6, lane = tid & 63;
  const int g = lane >> 4, r = lane & 15;
  const int row = tid >> 2, q = tid & 3;      // row in [16w,16w+16): band-aligned

  // one-time: W1 fragment table -> LDS (1280 x 16B)
  for (int i = tid; i < 1280; i += 256)
    *(u16x8*)&W1L[(size_t)i * 8] = *(const u16x8*)&w1p[(size_t)i * 8];

  // balanced tile range
  const int t0 = (int)((long long)blockIdx.x * ntiles / nblk);
  const int t1 = (int)((long long)(blockIdx.x + 1) * ntiles / nblk);
  if (t0 >= t1) { __syncthreads(); return; }

  const long long Emax = (long long)E - 1;

  // biases: acc[nb][i] = out[edge 16w+4g+i][ch nb*16+r]
  float b1v[4], b2v[4];
#pragma unroll
  for (int nb = 0; nb < 4; ++nb) { b1v[nb] = b1[nb * 16 + r]; b2v[nb] = b2[nb * 16 + r]; }

  // staging registers (tile t+1)
  unsigned long long nxt_aoe;
  u16x8 hs0, hs1, ht0, ht1;
  float4 fea, feb;

  auto load_aoe = [&](int t) -> unsigned long long {
    long long p = (long long)t * 64 + row;
    if (p > Emax) p = Emax;
    return aoe[p];
  };
  auto issue_gathers = [&](const unsigned long long u) {
    const int s = (int)(u >> 38);
    const int t = (int)((u >> 21) & 0x1FFFF);
    const int e = (int)(u & 0x1FFFFF);
    const u16x8* hs = (const u16x8*)(hb + (size_t)s * 64);
    const u16x8* ht = (const u16x8*)(hb + (size_t)t * 64);
    hs0 = hs[2 * q]; hs1 = hs[2 * q + 1];
    ht0 = ht[2 * q]; ht1 = ht[2 * q + 1];
    const float4* fp = (const float4*)(ef + (size_t)e * 32);
    fea = fp[2 * q]; feb = fp[2 * q + 1];
  };
  auto write_tile = [&](int t, const unsigned long long u) {   // own band rows only
    *(u16x8*)&X[row * SXE + 16 * q] = hs0;
    *(u16x8*)&X[row * SXE + 16 * q + 8] = hs1;
    *(u16x8*)&X[row * SXE + 64 + 16 * q] = ht0;
    *(u16x8*)&X[row * SXE + 64 + 16 * q + 8] = ht1;
    *(u16x8*)&X[row * SXE + 128 + 8 * q] = pack8(fea, feb);
    if (q == 0) tgts[t & 1][row] = ((long long)t * 64 + row < E)
                                       ? (int)((u >> 21) & 0x1FFFF) : -1;
  };

  // prologue: stage own band of tile t0
  {
    const unsigned long long a0 = load_aoe(t0);
    nxt_aoe = load_aoe(t0 + 1 < t1 ? t0 + 1 : t0);
    issue_gathers(a0);
    write_tile(t0, a0);
  }
  __syncthreads();   // ONLY block-wide barrier: covers W1L fill (+ own staging)

  for (int t = t0; t < t1; ++t) {
    const bool have_next = (t + 1 < t1);

    // issue prefetch gathers for t+1 (consumed at write_tile mid-iteration)
    unsigned long long ga = nxt_aoe;
    if (have_next) {
      nxt_aoe = load_aoe(t + 2 < t1 ? t + 2 : t + 1);
      issue_gathers(ga);
    }

    // ---- layer 1: own 16 edges x ALL 64 channels, K=160 ----
    f32x4 acc[4];
#pragma unroll
    for (int nb = 0; nb < 4; ++nb)
      acc[nb] = (f32x4){b1v[nb], b1v[nb], b1v[nb], b1v[nb]};
    __builtin_amdgcn_s_setprio(1);
#pragma unroll
    for (int kk = 0; kk < 5; ++kk) {
      const s16x8 af = *(const s16x8*)&X[(16 * w + r) * SXE + kk * 32 + 8 * g];
#pragma unroll
      for (int nb = 0; nb < 4; ++nb) {
        const s16x8 bf = *(const s16x8*)&W1L[(size_t)((kk * 4 + g) * 64 + nb * 16 + r) * 8];
        acc[nb] = __builtin_amdgcn_mfma_f32_16x16x32_bf16(af, bf, acc[nb], 0, 0, 0);
      }
    }
    __builtin_amdgcn_s_setprio(0);

    // ---- relu -> X2 (own band rows); stage X for t+1 (own band rows) ----
#pragma unroll
    for (int nb = 0; nb < 4; ++nb)
#pragma unroll
      for (int i = 0; i < 4; ++i)
        X2[(16 * w + 4 * g + i) * SX2 + nb * 16 + r] = f2bf(fmaxf(acc[nb][i], 0.0f));
    if (have_next) write_tile(t + 1, ga);   // vmcnt wait for gathers lands here
    wait_lds();   // own X2 writes retired before own reads (wave-local)

    // ---- layer 2: own 16 edges x 64 out-channels; W2 frags from global (L1) ----
    const s16x8 af0 = *(const s16x8*)&X2[(16 * w + r) * SX2 + 8 * g];
    const s16x8 af1 = *(const s16x8*)&X2[(16 * w + r) * SX2 + 32 + 8 * g];
    f32x4 acc2[4];
#pragma unroll
    for (int nb = 0; nb < 4; ++nb)
      acc2[nb] = (f32x4){b2v[nb], b2v[nb], b2v[nb], b2v[nb]};
    __builtin_amdgcn_s_setprio(1);
#pragma unroll
    for (int nb = 0; nb < 4; ++nb) {
      const s16x8 bf0 = *(const s16x8*)(w2p + (size_t)((0 + g) * 64 + nb * 16 + r) * 8);
      const s16x8 bf1 = *(const s16x8*)(w2p + (size_t)((4 + g) * 64 + nb * 16 + r) * 8);
      acc2[nb] = __builtin_amdgcn_mfma_f32_16x16x32_bf16(af0, bf0, acc2[nb], 0, 0, 0);
      acc2[nb] = __builtin_amdgcn_mfma_f32_16x16x32_bf16(af1, bf1, acc2[nb], 0, 0, 0);
    }
    __builtin_amdgcn_s_setprio(0);

    // ---- messages -> X2 (own band rows) ----
#pragma unroll
    for (int nb = 0; nb < 4; ++nb)
#pragma unroll
      for (int i = 0; i < 4; ++i)
        X2[(16 * w + 4 * g + i) * SX2 + nb * 16 + r] = f2bf(acc2[nb][i]);
    wait_lds();   // own msg writes retired

    // ---- segmented reduce over own band ----
    {
      float sum = 0.0f;
      int curt = -1;
#pragma unroll 4
      for (int i = 0; i < 16; ++i) {
        const int rr = 16 * w + i;
        const int tt = tgts[t & 1][rr];              // own band, wave-uniform
        const float v = bf2f(X2[rr * SX2 + lane]);
        if (tt != curt) {
          if (curt >= 0) atomicAdd(agg + (size_t)curt * 64 + lane, sum);
          curt = tt;
          sum = 0.0f;
        }
        if (tt >= 0) sum += v;
      }
      if (curt >= 0) atomicAdd(agg + (size_t)curt * 64 + lane, sum);
    }
    wait_lds();   // reduce reads retired before next tile's relu writes
  }
}

// ---------------- node MLP (MFMA) ----------------
__global__ __launch_bounds__(256, 4)
void node_mlp_mfma(const unsigned short* __restrict__ hb, const float* __restrict__ agg,
                   const unsigned short* __restrict__ w1p, const float* __restrict__ b1,
                   const unsigned short* __restrict__ w2p, const float* __restrict__ b2,
                   float* __restrict__ out, int N) {
  __shared__ unsigned short X[64 * SXN];
  __shared__ unsigned short X2[64 * SX2];

  const int tid = threadIdx.x;
  const int w = tid >> 6, lane = tid & 63;
  const int g = lane >> 4, r = lane & 15;
  const long long base = (long long)blockIdx.x * 64;

  {
    const int row = tid >> 2, q = tid & 3;
    long long n = base + row;
    if (n >= N) n = N - 1;
    const u16x8* hr = (const u16x8*)(hb + (size_t)n * 64);
    *(u16x8*)&X[row * SXN + 16 * q] = hr[2 * q];
    *(u16x8*)&X[row * SXN + 16 * q + 8] = hr[2 * q + 1];
    const float4* ar = (const float4*)(agg + (size_t)n * 64);
    *(u16x8*)&X[row * SXN + 64 + 16 * q] = pack8(ar[4 * q], ar[4 * q + 1]);
    *(u16x8*)&X[row * SXN + 64 + 16 * q + 8] = pack8(ar[4 * q + 2], ar[4 * q + 3]);
  }
  __syncthreads();

  const int cb = w * 16;

  const float bias1 = b1[cb + r];
  f32x4 acc[4];
  acc[0] = acc[1] = acc[2] = acc[3] = (f32x4){bias1, bias1, bias1, bias1};
#pragma unroll
  for (int kk = 0; kk < 4; ++kk) {
    const s16x8 bf = *(const s16x8*)(w1p + (size_t)((kk * 4 + g) * 64 + cb + r) * 8);
#pragma unroll
    for (int er = 0; er < 4; ++er) {
      const s16x8 af = *(const s16x8*)&X[(er * 16 + r) * SXN + kk * 32 + 8 * g];
      acc[er] = __builtin_amdgcn_mfma_f32_16x16x32_bf16(af, bf, acc[er], 0, 0, 0);
    }
  }

#pragma unroll
  for (int er = 0; er < 4; ++er)
#pragma unroll
    for (int i = 0; i < 4; ++i)
      X2[(er * 16 + 4 * g + i) * SX2 + cb + r] = f2bf(fmaxf(acc[er][i], 0.0f));
  __syncthreads();

  const float bias2 = b2[cb + r];
  f32x4 a2[4];
  a2[0] = a2[1] = a2[2] = a2[3] = (f32x4){bias2, bias2, bias2, bias2};
#pragma unroll
  for (int kk = 0; kk < 2; ++kk) {
    const s16x8 bf = *(const s16x8*)(w2p + (size_t)((kk * 4 + g) * 64 + cb + r) * 8);
#pragma unroll
    for (int er = 0; er < 4; ++er) {
      const s16x8 af = *(const s16x8*)&X2[(er * 16 + r) * SX2 + kk * 32 + 8 * g];
      a2[er] = __builtin_amdgcn_mfma_f32_16x16x32_bf16(af, bf, a2[er], 0, 0, 0);
    }
  }

#pragma unroll
  for (int er = 0; er < 4; ++er)
#pragma unroll
    for (int i = 0; i < 4; ++i) {
      const long long n = base + er * 16 + 4 * g + i;
      if (n < N) out[n * 64 + cb + r] = a2[er][i];
    }
}

// ---------------- host ----------------
extern "C" void kernel_launch(void* const* d_in, const int* in_sizes, int n_in,
                              void* d_out, int out_size, void* d_ws, size_t ws_size,
                              hipStream_t stream) {
  const float* h   = (const float*)d_in[0];
  const int*   ei  = (const int*)d_in[1];
  const float* ef  = (const float*)d_in[2];
  const float* eW1 = (const float*)d_in[3];
  const float* eb1 = (const float*)d_in[4];
  const float* eW2 = (const float*)d_in[5];
  const float* eb2 = (const float*)d_in[6];
  const float* uW1 = (const float*)d_in[7];
  const float* ub1 = (const float*)d_in[8];
  const float* uW2 = (const float*)d_in[9];
  const float* ub2 = (const float*)d_in[10];
  float* out = (float*)d_out;

  const int N = in_sizes[0] / 64;   // 100000  (< 2^17 for u64 packing)
  const int E = in_sizes[1] / 2;    // 1600000 (< 2^21)
  const int NBUCK = (N + 511) >> 9; // 196 coarse buckets
  const int ntiles = (E + 63) / 64;
  const int nblk = ntiles < NBLK_EDGE ? ntiles : NBLK_EDGE;

  size_t off = 0;
  auto alloc = [&](size_t bytes) { size_t o = off; off += (bytes + 255) & ~(size_t)255; return o; };
  const size_t agg_off    = alloc((size_t)N * 64 * 4);   // 25.6 MB (atomic target)
  const size_t bhist_off  = alloc(256 * 4);              // adjacent: single memset
  const size_t bstart_off = alloc(256 * 4);
  const size_t bcur_off   = alloc(256 * 4);
  const size_t hb_off     = alloc((size_t)N * 64 * 2);
  const size_t w1p_off    = alloc((size_t)160 * 64 * 2);
  const size_t w2p_off    = alloc((size_t)64 * 64 * 2);
  const size_t uw1p_off   = alloc((size_t)128 * 64 * 2);
  const size_t uw2p_off   = alloc((size_t)64 * 64 * 2);
  const size_t bufA_off   = alloc((size_t)E * 8);        // 12.8 MB coarse-bucketed
  const size_t aoe_off    = alloc((size_t)E * 8);        // 12.8 MB fully sorted
  char* ws = (char*)d_ws;

  float*          agg  = (float*)(ws + agg_off);
  int*            bhist = (int*)(ws + bhist_off);
  int*            bstart = (int*)(ws + bstart_off);
  int*            bcursor = (int*)(ws + bcur_off);
  unsigned short* hb   = (unsigned short*)(ws + hb_off);
  unsigned short* w1p  = (unsigned short*)(ws + w1p_off);
  unsigned short* w2p  = (unsigned short*)(ws + w2p_off);
  unsigned short* uw1p = (unsigned short*)(ws + uw1p_off);
  unsigned short* uw2p = (unsigned short*)(ws + uw2p_off);
  unsigned long long* bufA = (unsigned long long*)(ws + bufA_off);
  unsigned long long* aoe  = (unsigned long long*)(ws + aoe_off);

  // zero agg + bhist in one memset (adjacent)
  hipMemsetAsync(ws + agg_off, 0, bhist_off + 256 * 4 - agg_off, stream);

  const long long htot = (long long)N * 64;
  const int conv_blocks = (int)((htot / 4 + 255) / 256);
  prep<<<conv_blocks + 13 + 1024, 256, 0, stream>>>(h, hb, htot, eW1, eW2, uW1, uW2,
                                                    w1p, w2p, uw1p, uw2p, ei, bhist, E,
                                                    conv_blocks);

  bscan<<<1, 256, 0, stream>>>(bhist, bstart, bcursor, NBUCK);
  bucket_scatter<<<(E + S1_CHUNK - 1) / S1_CHUNK, 256, 0, stream>>>(ei, bcursor, bufA, E);
  bucket_sort<<<NBUCK, 256, 0, stream>>>(bufA, bstart, bhist, aoe);

  edge_mlp_fused<<<nblk, 256, 0, stream>>>(hb, ef, w1p, eb1, w2p, eb2, aoe, agg, E, ntiles, nblk);
  node_mlp_mfma<<<(N + 63) / 64, 256, 0, stream>>>(hb, agg, uw1p, ub1, uw2p, ub2, out, N);
}

// Round 19
// 209.309 us; speedup vs baseline: 1.0662x; 1.0662x over previous
//
#include <hip/hip_runtime.h>
#include <hip/hip_bf16.h>

// MessagePassingLayer, FINAL (= Round 13, best measured: 209.5us).
// R18 post-mortem: barrier-free band-local variant ALSO lost (150us edge,
// occ 32.7% at 3 blk/CU) -- falsifier fired. Six structural attempts on the
// edge kernel (R12, R14-R18) each isolated a constraint: VALU additions hurt
// (R12), VGPR>64 spills under (256,4) (R14) or halves occupancy without it
// (R15), grid was already exactly resident (R16), same-reg reissue serializes
// (R17), barrier removal traded occupancy (R18). Conclusion: at 64 VGPR /
// 4 blk/CU the kernel is bound by HBM-random gather throughput interleaved
// with a fixed compute chain -- R13 is the practical plateau.
// Pipeline: prep (bf16 conv + weight frag pack + 196-bin hist) -> bscan ->
// bucket_scatter (block-local line-merged) -> bucket_sort (tgt-contiguous)
// -> edge_mlp_fused (MFMA 2-layer + lgkm-only barriers + band-local L2 +
// segmented atomic reduce) -> node_mlp_mfma.

typedef __attribute__((ext_vector_type(8))) short s16x8;     // MFMA A/B frag
typedef __attribute__((ext_vector_type(4))) float f32x4;     // MFMA C/D frag
typedef __attribute__((ext_vector_type(8))) unsigned short u16x8;

#define SXE 168   // edge X tile row stride (bf16)
#define SXN 136   // node X tile row stride
#define SX2 72    // activation/message tile stride
#define NBLK_EDGE 1024  // exactly 4 blocks/CU x 256 CU co-resident (39.4KB LDS)
#define S1_CHUNK 4096
#define S2_CAP 10240   // max records per bucket for LDS sort (mean ~8163)

__device__ __forceinline__ unsigned short f2bf(float f) {   // native RNE cvt
  __hip_bfloat16 b = __float2bfloat16(f);
  return __builtin_bit_cast(unsigned short, b);
}
__device__ __forceinline__ float bf2f(unsigned short s) {
  unsigned int u = ((unsigned int)s) << 16;
  return __builtin_bit_cast(float, u);
}
__device__ __forceinline__ u16x8 pack8(const float4 a, const float4 b) {
  u16x8 r;
  r[0] = f2bf(a.x); r[1] = f2bf(a.y); r[2] = f2bf(a.z); r[3] = f2bf(a.w);
  r[4] = f2bf(b.x); r[5] = f2bf(b.y); r[6] = f2bf(b.z); r[7] = f2bf(b.w);
  return r;
}

// workgroup barrier that waits LDS ops only -- does NOT drain vmcnt
__device__ __forceinline__ void bar_lgkm() {
  __builtin_amdgcn_sched_barrier(0);
  asm volatile("s_waitcnt lgkmcnt(0)" ::: "memory");
  __builtin_amdgcn_s_barrier();
  __builtin_amdgcn_sched_barrier(0);
}

// ---------------- fused pre-pass: conv_bf16 + pack_weights + bucket hist ----------------
__global__ void prep(const float* __restrict__ h, unsigned short* __restrict__ hb, long long htot,
                     const float* __restrict__ eW1, const float* __restrict__ eW2,
                     const float* __restrict__ uW1, const float* __restrict__ uW2,
                     unsigned short* __restrict__ w1p, unsigned short* __restrict__ w2p,
                     unsigned short* __restrict__ uw1p, unsigned short* __restrict__ uw2p,
                     const int* __restrict__ ei, int* __restrict__ bhist, int E,
                     int conv_blocks) {
  __shared__ int lh[256];
  const int b = blockIdx.x;
  const int tid = threadIdx.x;
  if (b < conv_blocks) {
    const long long i = ((long long)b * 256 + tid) * 4;
    if (i + 3 < htot) {
      const float4 v = *(const float4*)(h + i);
      ushort4 o;
      o.x = f2bf(v.x); o.y = f2bf(v.y); o.z = f2bf(v.z); o.w = f2bf(v.w);
      *(ushort4*)(hb + i) = o;
    } else {
      for (long long j = i; j < htot; ++j) hb[j] = f2bf(h[j]);
    }
  } else if (b < conv_blocks + 13) {
    const int t2 = (b - conv_blocks) * 256 + tid;
    if (t2 < 52 * 64) {
      const int c = t2 & 63;
      int kg = t2 >> 6;
      const float* src;
      unsigned short* dst;
      if (kg < 20)      { src = eW1; dst = w1p; }
      else if (kg < 28) { src = eW2; dst = w2p; kg -= 20; }
      else if (kg < 44) { src = uW1; dst = uw1p; kg -= 28; }
      else              { src = uW2; dst = uw2p; kg -= 44; }
#pragma unroll
      for (int e = 0; e < 8; ++e)
        dst[(size_t)(kg * 64 + c) * 8 + e] = f2bf(src[(size_t)(kg * 8 + e) * 64 + c]);
    }
  } else {
    // 196-bin bucket histogram of tgt>>9 (LDS-binned)
    lh[tid] = 0;
    __syncthreads();
    const int hbk = b - conv_blocks - 13;   // 1024 hist blocks
    for (long long e = (long long)hbk * 256 + tid; e < E; e += 1024LL * 256)
      atomicAdd(&lh[ei[E + e] >> 9], 1);
    __syncthreads();
    if (lh[tid]) atomicAdd(&bhist[tid], lh[tid]);
  }
}

// exclusive scan of <=256 bucket counts -> bstart, bcursor
__global__ void bscan(const int* __restrict__ bhist, int* __restrict__ bstart,
                      int* __restrict__ bcursor, int nbuck) {
  __shared__ int s[256];
  const int tid = threadIdx.x;
  const int v = (tid < nbuck) ? bhist[tid] : 0;
  s[tid] = v;
  __syncthreads();
  for (int off = 1; off < 256; off <<= 1) {
    int t = (tid >= off) ? s[tid - off] : 0;
    __syncthreads();
    s[tid] += t;
    __syncthreads();
  }
  const int excl = s[tid] - v;
  if (tid < nbuck) { bstart[tid] = excl; bcursor[tid] = excl; }
}

// S1: coarse bucket scatter. Block-local grouping -> same-L2 line merging.
__global__ __launch_bounds__(256)
void bucket_scatter(const int* __restrict__ ei, int* __restrict__ bcursor,
                    unsigned long long* __restrict__ bufA, int E) {
  __shared__ int lhist[256], lbase[256], lcur[256];
  const int tid = threadIdx.x;
  const long long c0 = (long long)blockIdx.x * S1_CHUNK;

  lhist[tid] = 0;
  __syncthreads();

  unsigned long long rec[16];
  int bk[16];
#pragma unroll
  for (int j = 0; j < 16; ++j) {
    const long long e = c0 + j * 256 + tid;      // coalesced
    if (e < E) {
      const int t = ei[E + e];
      const int s = ei[e];
      rec[j] = (unsigned long long)(unsigned int)e |
               ((unsigned long long)(unsigned int)t << 21) |
               ((unsigned long long)(unsigned int)s << 38);
      bk[j] = t >> 9;
      atomicAdd(&lhist[bk[j]], 1);
    } else {
      bk[j] = -1;
    }
  }
  __syncthreads();

  if (lhist[tid] > 0) lbase[tid] = atomicAdd(&bcursor[tid], lhist[tid]);
  lcur[tid] = 0;
  __syncthreads();

#pragma unroll
  for (int j = 0; j < 16; ++j) {
    if (bk[j] >= 0) {
      const int pos = lbase[bk[j]] + atomicAdd(&lcur[bk[j]], 1);
      bufA[pos] = rec[j];   // contiguous within (block, bucket) group
    }
  }
}

// S2: per-bucket LDS counting sort by tgt&511 -> exact-tgt contiguity.
__global__ __launch_bounds__(256)
void bucket_sort(const unsigned long long* __restrict__ bufA,
                 const int* __restrict__ bstart, const int* __restrict__ bhist,
                 unsigned long long* __restrict__ aoe) {
  __shared__ unsigned long long srec[S2_CAP];   // 80 KB
  __shared__ int khist[512];
  __shared__ int sdata[256];
  const int b = blockIdx.x;
  const int tid = threadIdx.x;
  const int s0 = bstart[b];
  const int nb = bhist[b];

  if (nb > S2_CAP) {   // pathological bucket: pass through unsorted (still correct)
    for (int i = tid; i < nb; i += 256) aoe[s0 + i] = bufA[s0 + i];
    return;
  }

  khist[tid] = 0;
  khist[tid + 256] = 0;
  __syncthreads();
  for (int i = tid; i < nb; i += 256) {
    const unsigned long long r = bufA[s0 + i];
    atomicAdd(&khist[(int)((r >> 21) & 511)], 1);
  }
  __syncthreads();

  // exclusive scan over 512 bins (thread owns bins 2t, 2t+1)
  const int a0 = khist[2 * tid], a1 = khist[2 * tid + 1];
  const int sum = a0 + a1;
  sdata[tid] = sum;
  __syncthreads();
  for (int off = 1; off < 256; off <<= 1) {
    int t = (tid >= off) ? sdata[tid - off] : 0;
    __syncthreads();
    sdata[tid] += t;
    __syncthreads();
  }
  const int excl = sdata[tid] - sum;
  khist[2 * tid] = excl;           // khist becomes the scatter cursor
  khist[2 * tid + 1] = excl + a0;
  __syncthreads();

  for (int i = tid; i < nb; i += 256) {
    const unsigned long long r = bufA[s0 + i];   // L2-hot re-read
    const int pos = atomicAdd(&khist[(int)((r >> 21) & 511)], 1);
    srec[pos] = r;
  }
  __syncthreads();
  for (int i = tid; i < nb; i += 256) aoe[s0 + i] = srec[i];   // coalesced
}

// ---------------- fused edge MLP: persistent, pipelined, 2 barriers/tile ----------------
// Fragment maps (mfma_f32_16x16x32_bf16, lane l: g=l>>4, r=l&15):
//   A[m][k]: m=r, k=8g+e   B[k][n]: n=r, k=8g+e   D[m][n]: n=r, m=4g+i
__global__ __launch_bounds__(256, 4)
void edge_mlp_fused(const unsigned short* __restrict__ hb, const float* __restrict__ ef,
                    const unsigned short* __restrict__ w1p, const float* __restrict__ b1,
                    const unsigned short* __restrict__ w2p, const float* __restrict__ b2,
                    const unsigned long long* __restrict__ aoe, float* __restrict__ agg,
                    int E, int ntiles, int tpb) {
  __shared__ unsigned short X[64 * SXE];    // 21.5 KB input tile (single buffer)
  __shared__ unsigned short X2[64 * SX2];   // 9.2 KB acts, then message tile
  __shared__ unsigned short W2L[64 * 64];   // 8 KB W2 fragment table (NOT registers: spill)
  __shared__ int tgts[2][64];

  const int tid = threadIdx.x;
  const int w = tid >> 6, lane = tid & 63;
  const int g = lane >> 4, r = lane & 15;
  const int row = tid >> 2, q = tid & 3;

  // one-time: W2 fragment table -> LDS (covered by prologue barrier)
  {
    const int i = tid * 16;
    *(u16x8*)&W2L[i] = *(const u16x8*)&w2p[i];
    *(u16x8*)&W2L[i + 8] = *(const u16x8*)&w2p[i + 8];
  }

  const int t0 = blockIdx.x * tpb;
  const int t1 = min(t0 + tpb, ntiles);
  if (t0 >= t1) return;

  const long long Emax = (long long)E - 1;
  const int cb = w * 16;

  // hoisted loop invariants: W1 fragments + biases in registers
  s16x8 bfrag1[5];
#pragma unroll
  for (int kk = 0; kk < 5; ++kk)
    bfrag1[kk] = *(const s16x8*)(w1p + (size_t)((kk * 4 + g) * 64 + cb + r) * 8);
  const float bias1 = b1[cb + r];
  float b2v[4];
#pragma unroll
  for (int nb = 0; nb < 4; ++nb) b2v[nb] = b2[nb * 16 + r];

  // staging registers (tile t+1)
  unsigned long long nxt_aoe;
  u16x8 hs0, hs1, ht0, ht1;
  float4 fea, feb;

  auto load_aoe = [&](int t) -> unsigned long long {
    long long p = (long long)t * 64 + row;
    if (p > Emax) p = Emax;
    return aoe[p];
  };
  auto issue_gathers = [&](const unsigned long long u) {
    const int s = (int)(u >> 38);
    const int t = (int)((u >> 21) & 0x1FFFF);
    const int e = (int)(u & 0x1FFFFF);
    const u16x8* hs = (const u16x8*)(hb + (size_t)s * 64);
    const u16x8* ht = (const u16x8*)(hb + (size_t)t * 64);
    hs0 = hs[2 * q]; hs1 = hs[2 * q + 1];
    ht0 = ht[2 * q]; ht1 = ht[2 * q + 1];
    const float4* fp = (const float4*)(ef + (size_t)e * 32);
    fea = fp[2 * q]; feb = fp[2 * q + 1];
  };
  auto write_tile = [&](int t, const unsigned long long u) {
    *(u16x8*)&X[row * SXE + 16 * q] = hs0;
    *(u16x8*)&X[row * SXE + 16 * q + 8] = hs1;
    *(u16x8*)&X[row * SXE + 64 + 16 * q] = ht0;
    *(u16x8*)&X[row * SXE + 64 + 16 * q + 8] = ht1;
    *(u16x8*)&X[row * SXE + 128 + 8 * q] = pack8(fea, feb);
    if (q == 0) tgts[t & 1][row] = ((long long)t * 64 + row < E)
                                       ? (int)((u >> 21) & 0x1FFFF) : -1;
  };

  // prologue: stage tile t0
  {
    const unsigned long long a0 = load_aoe(t0);
    nxt_aoe = load_aoe(t0 + 1 < t1 ? t0 + 1 : t0);
    issue_gathers(a0);
    write_tile(t0, a0);
  }
  bar_lgkm();

  for (int t = t0; t < t1; ++t) {
    const bool have_next = (t + 1 < t1);

    // issue prefetch: aoe for t+2 (oldest), gathers for t+1 -- stay in
    // flight across L1 + barrier A (lgkm-only, no vmcnt drain)
    unsigned long long ga = nxt_aoe;
    if (have_next) {
      nxt_aoe = load_aoe(t + 2 < t1 ? t + 2 : t + 1);
      issue_gathers(ga);
    }

    // ---- layer 1: wave w computes channels [cb,cb+16) for all 64 edges ----
    f32x4 acc[4];
    acc[0] = acc[1] = acc[2] = acc[3] = (f32x4){bias1, bias1, bias1, bias1};
    __builtin_amdgcn_s_setprio(1);
#pragma unroll
    for (int kk = 0; kk < 5; ++kk) {
#pragma unroll
      for (int er = 0; er < 4; ++er) {
        const s16x8 af = *(const s16x8*)&X[(er * 16 + r) * SXE + kk * 32 + 8 * g];
        acc[er] = __builtin_amdgcn_mfma_f32_16x16x32_bf16(af, bfrag1[kk], acc[er], 0, 0, 0);
      }
    }
    __builtin_amdgcn_s_setprio(0);

    bar_lgkm();   // A: X dead (all L1 reads done), prev reduce done -> X2 free

    // ---- relu -> X2 (cross-band); stage X for t+1 (X is dead) ----
#pragma unroll
    for (int er = 0; er < 4; ++er)
#pragma unroll
      for (int i = 0; i < 4; ++i)
        X2[(er * 16 + 4 * g + i) * SX2 + cb + r] = f2bf(fmaxf(acc[er][i], 0.0f));
    if (have_next) write_tile(t + 1, ga);   // vmcnt wait lands here only

    bar_lgkm();   // B: acts visible to all waves; X staged

    // ---- layer 2, band-local: wave w's 16 edges x all 64 out-channels ----
    const s16x8 af0 = *(const s16x8*)&X2[(16 * w + r) * SX2 + 8 * g];
    const s16x8 af1 = *(const s16x8*)&X2[(16 * w + r) * SX2 + 32 + 8 * g];
    f32x4 acc2[4];
#pragma unroll
    for (int nb = 0; nb < 4; ++nb)
      acc2[nb] = (f32x4){b2v[nb], b2v[nb], b2v[nb], b2v[nb]};
    __builtin_amdgcn_s_setprio(1);
#pragma unroll
    for (int nb = 0; nb < 4; ++nb) {
      const s16x8 bf0 = *(const s16x8*)&W2L[(size_t)((0 + g) * 64 + nb * 16 + r) * 8];
      const s16x8 bf1 = *(const s16x8*)&W2L[(size_t)((4 + g) * 64 + nb * 16 + r) * 8];
      acc2[nb] = __builtin_amdgcn_mfma_f32_16x16x32_bf16(af0, bf0, acc2[nb], 0, 0, 0);
      acc2[nb] = __builtin_amdgcn_mfma_f32_16x16x32_bf16(af1, bf1, acc2[nb], 0, 0, 0);
    }
    __builtin_amdgcn_s_setprio(0);

    // ---- messages -> X2, OWN band only (rows 16w..16w+15) ----
#pragma unroll
    for (int nb = 0; nb < 4; ++nb)
#pragma unroll
      for (int i = 0; i < 4; ++i)
        X2[(16 * w + 4 * g + i) * SX2 + nb * 16 + r] = f2bf(acc2[nb][i]);
    asm volatile("s_waitcnt lgkmcnt(0)" ::: "memory");   // own writes retired
    __builtin_amdgcn_sched_barrier(0);

    // ---- segmented reduce over own band (NO barrier needed) ----
    {
      float sum = 0.0f;
      int curt = -1;
#pragma unroll 4
      for (int i = 0; i < 16; ++i) {
        const int rr = 16 * w + i;
        const int tt = tgts[t & 1][rr];              // wave-uniform
        const float v = bf2f(X2[rr * SX2 + lane]);
        if (tt != curt) {
          if (curt >= 0) atomicAdd(agg + (size_t)curt * 64 + lane, sum);
          curt = tt;
          sum = 0.0f;
        }
        if (tt >= 0) sum += v;
      }
      if (curt >= 0) atomicAdd(agg + (size_t)curt * 64 + lane, sum);
    }
    // next iteration's barrier A orders reduce reads vs next relu writes
  }
}

// ---------------- node MLP (MFMA) ----------------
__global__ __launch_bounds__(256, 4)
void node_mlp_mfma(const unsigned short* __restrict__ hb, const float* __restrict__ agg,
                   const unsigned short* __restrict__ w1p, const float* __restrict__ b1,
                   const unsigned short* __restrict__ w2p, const float* __restrict__ b2,
                   float* __restrict__ out, int N) {
  __shared__ unsigned short X[64 * SXN];
  __shared__ unsigned short X2[64 * SX2];

  const int tid = threadIdx.x;
  const int w = tid >> 6, lane = tid & 63;
  const int g = lane >> 4, r = lane & 15;
  const long long base = (long long)blockIdx.x * 64;

  {
    const int row = tid >> 2, q = tid & 3;
    long long n = base + row;
    if (n >= N) n = N - 1;
    const u16x8* hr = (const u16x8*)(hb + (size_t)n * 64);
    *(u16x8*)&X[row * SXN + 16 * q] = hr[2 * q];
    *(u16x8*)&X[row * SXN + 16 * q + 8] = hr[2 * q + 1];
    const float4* ar = (const float4*)(agg + (size_t)n * 64);
    *(u16x8*)&X[row * SXN + 64 + 16 * q] = pack8(ar[4 * q], ar[4 * q + 1]);
    *(u16x8*)&X[row * SXN + 64 + 16 * q + 8] = pack8(ar[4 * q + 2], ar[4 * q + 3]);
  }
  __syncthreads();

  const int cb = w * 16;

  const float bias1 = b1[cb + r];
  f32x4 acc[4];
  acc[0] = acc[1] = acc[2] = acc[3] = (f32x4){bias1, bias1, bias1, bias1};
#pragma unroll
  for (int kk = 0; kk < 4; ++kk) {
    const s16x8 bf = *(const s16x8*)(w1p + (size_t)((kk * 4 + g) * 64 + cb + r) * 8);
#pragma unroll
    for (int er = 0; er < 4; ++er) {
      const s16x8 af = *(const s16x8*)&X[(er * 16 + r) * SXN + kk * 32 + 8 * g];
      acc[er] = __builtin_amdgcn_mfma_f32_16x16x32_bf16(af, bf, acc[er], 0, 0, 0);
    }
  }

#pragma unroll
  for (int er = 0; er < 4; ++er)
#pragma unroll
    for (int i = 0; i < 4; ++i)
      X2[(er * 16 + 4 * g + i) * SX2 + cb + r] = f2bf(fmaxf(acc[er][i], 0.0f));
  __syncthreads();

  const float bias2 = b2[cb + r];
  f32x4 a2[4];
  a2[0] = a2[1] = a2[2] = a2[3] = (f32x4){bias2, bias2, bias2, bias2};
#pragma unroll
  for (int kk = 0; kk < 2; ++kk) {
    const s16x8 bf = *(const s16x8*)(w2p + (size_t)((kk * 4 + g) * 64 + cb + r) * 8);
#pragma unroll
    for (int er = 0; er < 4; ++er) {
      const s16x8 af = *(const s16x8*)&X2[(er * 16 + r) * SX2 + kk * 32 + 8 * g];
      a2[er] = __builtin_amdgcn_mfma_f32_16x16x32_bf16(af, bf, a2[er], 0, 0, 0);
    }
  }

#pragma unroll
  for (int er = 0; er < 4; ++er)
#pragma unroll
    for (int i = 0; i < 4; ++i) {
      const long long n = base + er * 16 + 4 * g + i;
      if (n < N) out[n * 64 + cb + r] = a2[er][i];
    }
}

// ---------------- host ----------------
extern "C" void kernel_launch(void* const* d_in, const int* in_sizes, int n_in,
                              void* d_out, int out_size, void* d_ws, size_t ws_size,
                              hipStream_t stream) {
  const float* h   = (const float*)d_in[0];
  const int*   ei  = (const int*)d_in[1];
  const float* ef  = (const float*)d_in[2];
  const float* eW1 = (const float*)d_in[3];
  const float* eb1 = (const float*)d_in[4];
  const float* eW2 = (const float*)d_in[5];
  const float* eb2 = (const float*)d_in[6];
  const float* uW1 = (const float*)d_in[7];
  const float* ub1 = (const float*)d_in[8];
  const float* uW2 = (const float*)d_in[9];
  const float* ub2 = (const float*)d_in[10];
  float* out = (float*)d_out;

  const int N = in_sizes[0] / 64;   // 100000  (< 2^17 for u64 packing)
  const int E = in_sizes[1] / 2;    // 1600000 (< 2^21)
  const int NBUCK = (N + 511) >> 9; // 196 coarse buckets
  const int ntiles = (E + 63) / 64;
  const int nblk = ntiles < NBLK_EDGE ? ntiles : NBLK_EDGE;
  const int tpb = (ntiles + nblk - 1) / nblk;

  size_t off = 0;
  auto alloc = [&](size_t bytes) { size_t o = off; off += (bytes + 255) & ~(size_t)255; return o; };
  const size_t agg_off    = alloc((size_t)N * 64 * 4);   // 25.6 MB (atomic target)
  const size_t bhist_off  = alloc(256 * 4);              // adjacent: single memset
  const size_t bstart_off = alloc(256 * 4);
  const size_t bcur_off   = alloc(256 * 4);
  const size_t hb_off     = alloc((size_t)N * 64 * 2);
  const size_t w1p_off    = alloc((size_t)160 * 64 * 2);
  const size_t w2p_off    = alloc((size_t)64 * 64 * 2);
  const size_t uw1p_off   = alloc((size_t)128 * 64 * 2);
  const size_t uw2p_off   = alloc((size_t)64 * 64 * 2);
  const size_t bufA_off   = alloc((size_t)E * 8);        // 12.8 MB coarse-bucketed
  const size_t aoe_off    = alloc((size_t)E * 8);        // 12.8 MB fully sorted
  char* ws = (char*)d_ws;

  float*          agg  = (float*)(ws + agg_off);
  int*            bhist = (int*)(ws + bhist_off);
  int*            bstart = (int*)(ws + bstart_off);
  int*            bcursor = (int*)(ws + bcur_off);
  unsigned short* hb   = (unsigned short*)(ws + hb_off);
  unsigned short* w1p  = (unsigned short*)(ws + w1p_off);
  unsigned short* w2p  = (unsigned short*)(ws + w2p_off);
  unsigned short* uw1p = (unsigned short*)(ws + uw1p_off);
  unsigned short* uw2p = (unsigned short*)(ws + uw2p_off);
  unsigned long long* bufA = (unsigned long long*)(ws + bufA_off);
  unsigned long long* aoe  = (unsigned long long*)(ws + aoe_off);

  // zero agg + bhist in one memset (adjacent)
  hipMemsetAsync(ws + agg_off, 0, bhist_off + 256 * 4 - agg_off, stream);

  const long long htot = (long long)N * 64;
  const int conv_blocks = (int)((htot / 4 + 255) / 256);
  prep<<<conv_blocks + 13 + 1024, 256, 0, stream>>>(h, hb, htot, eW1, eW2, uW1, uW2,
                                                    w1p, w2p, uw1p, uw2p, ei, bhist, E,
                                                    conv_blocks);

  bscan<<<1, 256, 0, stream>>>(bhist, bstart, bcursor, NBUCK);
  bucket_scatter<<<(E + S1_CHUNK - 1) / S1_CHUNK, 256, 0, stream>>>(ei, bcursor, bufA, E);
  bucket_sort<<<NBUCK, 256, 0, stream>>>(bufA, bstart, bhist, aoe);

  edge_mlp_fused<<<nblk, 256, 0, stream>>>(hb, ef, w1p, eb1, w2p, eb2, aoe, agg, E, ntiles, tpb);
  node_mlp_mfma<<<(N + 63) / 64, 256, 0, stream>>>(hb, agg, uw1p, ub1, uw2p, ub2, out, N);
}